// Round 1
// baseline (876.019 us; speedup 1.0000x reference)
//
#include <hip/hip_runtime.h>

#define NG 20000
#define NC 50000
#define NT 8000
#define EGC 600000
#define EGT 200000

// ---------------- CSR build kernels ----------------

static __global__ void hist_kernel(const int* __restrict__ src, const int* __restrict__ dst,
                                   int ne, int* __restrict__ cnt_out, int* __restrict__ cnt_in) {
    int i = blockIdx.x * blockDim.x + threadIdx.x;
    if (i < ne) {
        atomicAdd(&cnt_out[src[i]], 1);
        atomicAdd(&cnt_in[dst[i]], 1);
    }
}

static __global__ void scales_kernel(const int* __restrict__ cnt_out, float* __restrict__ so, int n_src,
                                     const int* __restrict__ cnt_in, float* __restrict__ si, int n_dst) {
    int i = blockIdx.x * blockDim.x + threadIdx.x;
    if (i < n_src) {
        int c = cnt_out[i]; if (c < 1) c = 1;
        so[i] = 1.0f / sqrtf((float)c);
    }
    if (i < n_dst) {
        int c = cnt_in[i]; if (c < 1) c = 1;
        si[i] = 1.0f / sqrtf((float)c);
    }
}

static __device__ void scan_body(const int* __restrict__ cnt, int* __restrict__ off, int n) {
    __shared__ int partial[256];
    int t = threadIdx.x;
    int chunk = (n + 255) >> 8;
    int begin = t * chunk;
    int end = min(begin + chunk, n);
    int s = 0;
    for (int i = begin; i < end; ++i) s += cnt[i];
    partial[t] = s;
    __syncthreads();
    if (t == 0) {
        int acc = 0;
        for (int i = 0; i < 256; ++i) { int v = partial[i]; partial[i] = acc; acc += v; }
    }
    __syncthreads();
    int acc = partial[t];
    for (int i = begin; i < end; ++i) { off[i] = acc; acc += cnt[i]; }
    if (begin <= n && end == n) off[n] = acc;
}

static __global__ void scan4_kernel(const int* c0, int* o0, int n0,
                                    const int* c1, int* o1, int n1,
                                    const int* c2, int* o2, int n2,
                                    const int* c3, int* o3, int n3) {
    if (blockIdx.x == 0) scan_body(c0, o0, n0);
    else if (blockIdx.x == 1) scan_body(c1, o1, n1);
    else if (blockIdx.x == 2) scan_body(c2, o2, n2);
    else scan_body(c3, o3, n3);
}

static __global__ void fill_kernel(const int* __restrict__ src, const int* __restrict__ dst, int ne,
                                   const int* __restrict__ off, int* __restrict__ cursor,
                                   int* __restrict__ eid) {
    int i = blockIdx.x * blockDim.x + threadIdx.x;
    if (i < ne) {
        int d = dst[i];
        int p = atomicAdd(&cursor[d], 1);
        eid[off[d] + p] = src[i];
    }
}

// ---------------- dense GEMM: out[n,128] = opt_relu((X * rs) @ W + bias) ----------------
// block = 256 threads computes 32 rows x 128 cols; thread: 4 rows x 4 cols.

template<int RELU>
static __global__ __launch_bounds__(256)
void gemm_kernel(const float* __restrict__ X, const float* __restrict__ rs,
                 const float* __restrict__ W, const float* __restrict__ bias,
                 float* __restrict__ out, int n) {
    __shared__ float xs[32][128];
    const int r0 = blockIdx.x * 32;
    const int t = threadIdx.x;
    for (int i = t; i < 1024; i += 256) {
        int r = i >> 5;
        int c4 = i & 31;
        int row = r0 + r;
        float4 v = make_float4(0.f, 0.f, 0.f, 0.f);
        if (row < n) {
            v = reinterpret_cast<const float4*>(X)[row * 32 + c4];
            if (rs) { float s = rs[row]; v.x *= s; v.y *= s; v.z *= s; v.w *= s; }
        }
        reinterpret_cast<float4*>(&xs[r][0])[c4] = v;
    }
    __syncthreads();
    const int tx = t & 31, ty = t >> 5;
    const int c0 = tx << 2;
    float acc[4][4] = {};
    const float* wp = W + c0;
    for (int k = 0; k < 128; k += 4) {
        float4 w0 = *reinterpret_cast<const float4*>(wp + (k + 0) * 128);
        float4 w1 = *reinterpret_cast<const float4*>(wp + (k + 1) * 128);
        float4 w2 = *reinterpret_cast<const float4*>(wp + (k + 2) * 128);
        float4 w3 = *reinterpret_cast<const float4*>(wp + (k + 3) * 128);
#pragma unroll
        for (int i = 0; i < 4; ++i) {
            float4 xv = *reinterpret_cast<const float4*>(&xs[ty * 4 + i][k]);
            acc[i][0] += xv.x * w0.x; acc[i][1] += xv.x * w0.y; acc[i][2] += xv.x * w0.z; acc[i][3] += xv.x * w0.w;
            acc[i][0] += xv.y * w1.x; acc[i][1] += xv.y * w1.y; acc[i][2] += xv.y * w1.z; acc[i][3] += xv.y * w1.w;
            acc[i][0] += xv.z * w2.x; acc[i][1] += xv.z * w2.y; acc[i][2] += xv.z * w2.z; acc[i][3] += xv.z * w2.w;
            acc[i][0] += xv.w * w3.x; acc[i][1] += xv.w * w3.y; acc[i][2] += xv.w * w3.z; acc[i][3] += xv.w * w3.w;
        }
    }
    float4 bv = make_float4(0.f, 0.f, 0.f, 0.f);
    if (bias) bv = reinterpret_cast<const float4*>(bias)[tx];
#pragma unroll
    for (int i = 0; i < 4; ++i) {
        int row = r0 + ty * 4 + i;
        if (row < n) {
            float4 o;
            o.x = acc[i][0] + bv.x; o.y = acc[i][1] + bv.y;
            o.z = acc[i][2] + bv.z; o.w = acc[i][3] + bv.w;
            if (RELU) {
                o.x = fmaxf(o.x, 0.f); o.y = fmaxf(o.y, 0.f);
                o.z = fmaxf(o.z, 0.f); o.w = fmaxf(o.w, 0.f);
            }
            reinterpret_cast<float4*>(out)[row * 32 + tx] = o;
        }
    }
}

// ---------------- CSR aggregation: one wave per dst row ----------------
// MODE 0: out = sum (raw)          (pre-scale optional)
// MODE 1: out = relu(si*sum + b)   (write)
// MODE 2: out += relu(si*sum + b)  (accumulate)

template<int MODE>
static __global__ __launch_bounds__(256)
void agg_kernel(const float* __restrict__ h, const float* __restrict__ pre,
                const int* __restrict__ off, const int* __restrict__ eid,
                const float* __restrict__ si, const float* __restrict__ bias,
                float* __restrict__ out, int n_dst) {
    int row = blockIdx.x * 4 + (threadIdx.x >> 6);
    if (row >= n_dst) return;
    int lane = threadIdx.x & 63;
    int e0 = off[row], e1 = off[row + 1];
    float ax = 0.f, ay = 0.f;
    const float2* h2 = reinterpret_cast<const float2*>(h);
    int j = e0;
    for (; j + 4 <= e1; j += 4) {
        int s0 = eid[j], s1 = eid[j + 1], s2 = eid[j + 2], s3 = eid[j + 3];
        float2 v0 = h2[s0 * 64 + lane];
        float2 v1 = h2[s1 * 64 + lane];
        float2 v2 = h2[s2 * 64 + lane];
        float2 v3 = h2[s3 * 64 + lane];
        if (pre) {
            float p0 = pre[s0], p1 = pre[s1], p2 = pre[s2], p3 = pre[s3];
            ax += v0.x * p0 + v1.x * p1 + v2.x * p2 + v3.x * p3;
            ay += v0.y * p0 + v1.y * p1 + v2.y * p2 + v3.y * p3;
        } else {
            ax += v0.x + v1.x + v2.x + v3.x;
            ay += v0.y + v1.y + v2.y + v3.y;
        }
    }
    for (; j < e1; ++j) {
        int s = eid[j];
        float2 v = h2[s * 64 + lane];
        float pp = pre ? pre[s] : 1.0f;
        ax += v.x * pp; ay += v.y * pp;
    }
    float2* o2 = reinterpret_cast<float2*>(out) + row * 64 + lane;
    if (MODE == 0) {
        *o2 = make_float2(ax, ay);
    } else {
        float s = si[row];
        float2 b = reinterpret_cast<const float2*>(bias)[lane];
        float ox = fmaxf(ax * s + b.x, 0.f);
        float oy = fmaxf(ay * s + b.y, 0.f);
        if (MODE == 2) { float2 cur = *o2; ox += cur.x; oy += cur.y; }
        *o2 = make_float2(ox, oy);
    }
}

// ---------------- orchestration ----------------

extern "C" void kernel_launch(void* const* d_in, const int* in_sizes, int n_in,
                              void* d_out, int out_size, void* d_ws, size_t ws_size,
                              hipStream_t stream) {
    const float* x_cell   = (const float*)d_in[1];
    const float* x_gotem  = (const float*)d_in[2];
    const float* W_eg_c2g = (const float*)d_in[3];  const float* b_eg_c2g = (const float*)d_in[4];
    const float* W_eg_t2g = (const float*)d_in[5];  const float* b_eg_t2g = (const float*)d_in[6];
    const float* W1_g2c   = (const float*)d_in[11]; const float* b1_g2c   = (const float*)d_in[12];
    const float* W1_g2t   = (const float*)d_in[15]; const float* b1_g2t   = (const float*)d_in[16];
    const float* W2_c2g   = (const float*)d_in[21]; const float* b2_c2g   = (const float*)d_in[22];
    const float* W2_t2g   = (const float*)d_in[25]; const float* b2_t2g   = (const float*)d_in[26];
    const float* W3_g2c   = (const float*)d_in[27]; const float* b3_g2c   = (const float*)d_in[28];
    const float* Wd_cell  = (const float*)d_in[29]; const float* bd_cell  = (const float*)d_in[30];
    const int* eg2c_src = (const int*)d_in[31]; const int* eg2c_dst = (const int*)d_in[32];
    const int* ec2g_src = (const int*)d_in[33]; const int* ec2g_dst = (const int*)d_in[34];
    const int* eg2t_src = (const int*)d_in[35]; const int* eg2t_dst = (const int*)d_in[36];
    const int* et2g_src = (const int*)d_in[37]; const int* et2g_dst = (const int*)d_in[38];

    char* p = (char*)d_ws;
    auto alloc = [&](size_t bytes) { char* r = p; p += (bytes + 255) & ~(size_t)255; return r; };
    float* h_buf = (float*)alloc((size_t)NC * 128 * 4);   // scratch h / agg-first A
    float* g_buf = (float*)alloc((size_t)NG * 128 * 4);   // g, then g2
    float* c_buf = (float*)alloc((size_t)NC * 128 * 4);   // c1, then c3
    float* t_buf = (float*)alloc((size_t)NT * 128 * 4);   // t1
    int* off_gc = (int*)alloc((NG + 1) * 4);  int* eid_gc = (int*)alloc((size_t)EGC * 4); // ec2g (dst=gene)
    int* off_gt = (int*)alloc((NG + 1) * 4);  int* eid_gt = (int*)alloc((size_t)EGT * 4); // et2g (dst=gene)
    int* off_c  = (int*)alloc((NC + 1) * 4);  int* eid_c  = (int*)alloc((size_t)EGC * 4); // eg2c (dst=cell)
    int* off_t  = (int*)alloc((NT + 1) * 4);  int* eid_t  = (int*)alloc((size_t)EGT * 4); // eg2t (dst=gotem)
    float* so_ec2g = (float*)alloc(NC * 4);
    float* so_et2g = (float*)alloc(NT * 4);
    float* so_eg2c = (float*)alloc(NG * 4);
    float* so_eg2t = (float*)alloc(NG * 4);
    float* si_ec2g = (float*)alloc(NG * 4);
    float* si_et2g = (float*)alloc(NG * 4);
    float* si_eg2c = (float*)alloc(NC * 4);
    float* si_eg2t = (float*)alloc(NT * 4);
    char* cnt_base = alloc(0);
    int* co_ec2g = (int*)alloc(NC * 4); int* ci_ec2g = (int*)alloc(NG * 4); int* cu_ec2g = (int*)alloc(NG * 4);
    int* co_et2g = (int*)alloc(NT * 4); int* ci_et2g = (int*)alloc(NG * 4); int* cu_et2g = (int*)alloc(NG * 4);
    int* co_eg2c = (int*)alloc(NG * 4); int* ci_eg2c = (int*)alloc(NC * 4); int* cu_eg2c = (int*)alloc(NC * 4);
    int* co_eg2t = (int*)alloc(NG * 4); int* ci_eg2t = (int*)alloc(NT * 4); int* cu_eg2t = (int*)alloc(NT * 4);
    size_t cnt_bytes = (size_t)(p - cnt_base);
    hipMemsetAsync(cnt_base, 0, cnt_bytes, stream);

    auto cdiv = [](int a, int b) { return (a + b - 1) / b; };

    // ---- CSR + degree build (4 edge types) ----
    hist_kernel<<<cdiv(EGC, 256), 256, 0, stream>>>(ec2g_src, ec2g_dst, EGC, co_ec2g, ci_ec2g);
    hist_kernel<<<cdiv(EGT, 256), 256, 0, stream>>>(et2g_src, et2g_dst, EGT, co_et2g, ci_et2g);
    hist_kernel<<<cdiv(EGC, 256), 256, 0, stream>>>(eg2c_src, eg2c_dst, EGC, co_eg2c, ci_eg2c);
    hist_kernel<<<cdiv(EGT, 256), 256, 0, stream>>>(eg2t_src, eg2t_dst, EGT, co_eg2t, ci_eg2t);
    scales_kernel<<<cdiv(NC, 256), 256, 0, stream>>>(co_ec2g, so_ec2g, NC, ci_ec2g, si_ec2g, NG);
    scales_kernel<<<cdiv(NG, 256), 256, 0, stream>>>(co_et2g, so_et2g, NT, ci_et2g, si_et2g, NG);
    scales_kernel<<<cdiv(NC, 256), 256, 0, stream>>>(co_eg2c, so_eg2c, NG, ci_eg2c, si_eg2c, NC);
    scales_kernel<<<cdiv(NG, 256), 256, 0, stream>>>(co_eg2t, so_eg2t, NG, ci_eg2t, si_eg2t, NT);
    scan4_kernel<<<4, 256, 0, stream>>>(ci_ec2g, off_gc, NG, ci_et2g, off_gt, NG,
                                        ci_eg2c, off_c, NC, ci_eg2t, off_t, NT);
    fill_kernel<<<cdiv(EGC, 256), 256, 0, stream>>>(ec2g_src, ec2g_dst, EGC, off_gc, cu_ec2g, eid_gc);
    fill_kernel<<<cdiv(EGT, 256), 256, 0, stream>>>(et2g_src, et2g_dst, EGT, off_gt, cu_et2g, eid_gt);
    fill_kernel<<<cdiv(EGC, 256), 256, 0, stream>>>(eg2c_src, eg2c_dst, EGC, off_c, cu_eg2c, eid_c);
    fill_kernel<<<cdiv(EGT, 256), 256, 0, stream>>>(eg2t_src, eg2t_dst, EGT, off_t, cu_eg2t, eid_t);

    // ---- Layer E: g = relu(gconv(x_cell via ec2g) + gconv(x_gotem via et2g)) ----
    // part A agg-first (NC src -> NG GEMM rows)
    agg_kernel<0><<<cdiv(NG, 4), 256, 0, stream>>>(x_cell, so_ec2g, off_gc, eid_gc, nullptr, nullptr, h_buf, NG);
    gemm_kernel<1><<<cdiv(NG, 32), 256, 0, stream>>>(h_buf, si_ec2g, W_eg_c2g, b_eg_c2g, g_buf, NG);
    // part B gemm-first (NT = 8000 rows)
    gemm_kernel<0><<<cdiv(NT, 32), 256, 0, stream>>>(x_gotem, so_et2g, W_eg_t2g, nullptr, h_buf, NT);
    agg_kernel<2><<<cdiv(NG, 4), 256, 0, stream>>>(h_buf, nullptr, off_gt, eid_gt, si_et2g, b_eg_t2g, g_buf, NG);

    // ---- c1 = gconv(g via eg2c): gemm-first (NG=20k rows) ----
    gemm_kernel<0><<<cdiv(NG, 32), 256, 0, stream>>>(g_buf, so_eg2c, W1_g2c, nullptr, h_buf, NG);
    agg_kernel<1><<<cdiv(NC, 4), 256, 0, stream>>>(h_buf, nullptr, off_c, eid_c, si_eg2c, b1_g2c, c_buf, NC);

    // ---- t1 = gconv(g via eg2t): agg-first (NT=8k GEMM rows) ----
    agg_kernel<0><<<cdiv(NT, 4), 256, 0, stream>>>(g_buf, so_eg2t, off_t, eid_t, nullptr, nullptr, h_buf, NT);
    gemm_kernel<1><<<cdiv(NT, 32), 256, 0, stream>>>(h_buf, si_eg2t, W1_g2t, b1_g2t, t_buf, NT);

    // ---- g2 = gconv(c1 via ec2g) + gconv(t1 via et2g) (reuse g_buf) ----
    agg_kernel<0><<<cdiv(NG, 4), 256, 0, stream>>>(c_buf, so_ec2g, off_gc, eid_gc, nullptr, nullptr, h_buf, NG);
    gemm_kernel<1><<<cdiv(NG, 32), 256, 0, stream>>>(h_buf, si_ec2g, W2_c2g, b2_c2g, g_buf, NG);
    gemm_kernel<0><<<cdiv(NT, 32), 256, 0, stream>>>(t_buf, so_et2g, W2_t2g, nullptr, h_buf, NT);
    agg_kernel<2><<<cdiv(NG, 4), 256, 0, stream>>>(h_buf, nullptr, off_gt, eid_gt, si_et2g, b2_t2g, g_buf, NG);

    // ---- c3 = gconv(g2 via eg2c) (reuse c_buf) ----
    gemm_kernel<0><<<cdiv(NG, 32), 256, 0, stream>>>(g_buf, so_eg2c, W3_g2c, nullptr, h_buf, NG);
    agg_kernel<1><<<cdiv(NC, 4), 256, 0, stream>>>(h_buf, nullptr, off_c, eid_c, si_eg2c, b3_g2c, c_buf, NC);

    // ---- out = c3 @ Wd_cell + bd_cell ----
    gemm_kernel<0><<<cdiv(NC, 32), 256, 0, stream>>>(c_buf, nullptr, Wd_cell, bd_cell, (float*)d_out, NC);
}

// Round 2
// 819.034 us; speedup vs baseline: 1.0696x; 1.0696x over previous
//
#include <hip/hip_runtime.h>

#define NG 20000
#define NC 50000
#define NT 8000
#define EGC 600000
#define EGT 200000

// ---------------- CSR build kernels ----------------

struct EdgeSeg { const int* src; const int* dst; int ne; int* co; int* ci; };

static __global__ __launch_bounds__(256)
void hist4_kernel(EdgeSeg a, EdgeSeg b, EdgeSeg c, EdgeSeg d) {
    int i = blockIdx.x * 256 + threadIdx.x;
    if (i < a.ne) { atomicAdd(&a.co[a.src[i]], 1); atomicAdd(&a.ci[a.dst[i]], 1); return; }
    i -= a.ne;
    if (i < b.ne) { atomicAdd(&b.co[b.src[i]], 1); atomicAdd(&b.ci[b.dst[i]], 1); return; }
    i -= b.ne;
    if (i < c.ne) { atomicAdd(&c.co[c.src[i]], 1); atomicAdd(&c.ci[c.dst[i]], 1); return; }
    i -= c.ne;
    if (i < d.ne) { atomicAdd(&d.co[d.src[i]], 1); atomicAdd(&d.ci[d.dst[i]], 1); }
}

struct ScaleSeg { const int* co; float* so; int ns; const int* ci; float* si; int nd; int len; };

static __device__ void scale_seg_body(const ScaleSeg& s, int i) {
    if (i < s.ns) {
        int c = s.co[i]; if (c < 1) c = 1;
        s.so[i] = 1.0f / sqrtf((float)c);
    }
    if (i < s.nd) {
        int c = s.ci[i]; if (c < 1) c = 1;
        s.si[i] = 1.0f / sqrtf((float)c);
    }
}

static __global__ __launch_bounds__(256)
void scales4_kernel(ScaleSeg a, ScaleSeg b, ScaleSeg c, ScaleSeg d) {
    int i = blockIdx.x * 256 + threadIdx.x;
    if (i < a.len) { scale_seg_body(a, i); return; }
    i -= a.len;
    if (i < b.len) { scale_seg_body(b, i); return; }
    i -= b.len;
    if (i < c.len) { scale_seg_body(c, i); return; }
    i -= c.len;
    if (i < d.len) { scale_seg_body(d, i); }
}

// Tiled block scan: 1024 threads, wave shfl scan + warp-sum LDS scan + carry.
static __device__ void scan_body(const int* __restrict__ cnt, int* __restrict__ off, int n) {
    __shared__ int wsum[16];
    __shared__ int carry_s, total_s;
    const int t = threadIdx.x;
    const int lane = t & 63, wid = t >> 6;
    if (t == 0) carry_s = 0;
    __syncthreads();
    for (int base = 0; base < n; base += 1024) {
        int i = base + t;
        int v = (i < n) ? cnt[i] : 0;
        int x = v;
#pragma unroll
        for (int d = 1; d < 64; d <<= 1) {
            int y = __shfl_up(x, d, 64);
            if (lane >= d) x += y;
        }
        if (lane == 63) wsum[wid] = x;
        __syncthreads();
        if (wid == 0) {
            int w = (lane < 16) ? wsum[lane] : 0;
            int xx = w;
#pragma unroll
            for (int d = 1; d < 16; d <<= 1) {
                int y = __shfl_up(xx, d, 64);
                if (lane >= d) xx += y;
            }
            if (lane < 16) wsum[lane] = xx - w;   // exclusive warp prefix
            if (lane == 15) total_s = xx;         // tile total
        }
        __syncthreads();
        int carry = carry_s;
        if (i < n) off[i] = carry + wsum[wid] + (x - v);
        __syncthreads();
        if (t == 0) carry_s = carry + total_s;
        __syncthreads();
    }
    if (t == 0) off[n] = carry_s;
}

static __global__ __launch_bounds__(1024)
void scan4_kernel(const int* c0, int* o0, int n0,
                  const int* c1, int* o1, int n1,
                  const int* c2, int* o2, int n2,
                  const int* c3, int* o3, int n3) {
    if (blockIdx.x == 0) scan_body(c0, o0, n0);
    else if (blockIdx.x == 1) scan_body(c1, o1, n1);
    else if (blockIdx.x == 2) scan_body(c2, o2, n2);
    else scan_body(c3, o3, n3);
}

struct FillSeg { const int* src; const int* dst; int ne; const int* off; int* cur; int* eid; };

static __device__ void fill_seg_body(const FillSeg& f, int i) {
    int d = f.dst[i];
    int p = atomicAdd(&f.cur[d], 1);
    f.eid[f.off[d] + p] = f.src[i];
}

static __global__ __launch_bounds__(256)
void fill4_kernel(FillSeg a, FillSeg b, FillSeg c, FillSeg d) {
    int i = blockIdx.x * 256 + threadIdx.x;
    if (i < a.ne) { fill_seg_body(a, i); return; }
    i -= a.ne;
    if (i < b.ne) { fill_seg_body(b, i); return; }
    i -= b.ne;
    if (i < c.ne) { fill_seg_body(c, i); return; }
    i -= c.ne;
    if (i < d.ne) { fill_seg_body(d, i); }
}

// ---------------- dense GEMM: out[n,128] = opt_relu((X * rs) @ W + bias) ----------------
// block = 256 threads computes 32 rows x 128 cols; thread: 4 rows x 4 cols.

template<int RELU>
static __global__ __launch_bounds__(256)
void gemm_kernel(const float* __restrict__ X, const float* __restrict__ rs,
                 const float* __restrict__ W, const float* __restrict__ bias,
                 float* __restrict__ out, int n) {
    __shared__ float xs[32][128];
    const int r0 = blockIdx.x * 32;
    const int t = threadIdx.x;
    for (int i = t; i < 1024; i += 256) {
        int r = i >> 5;
        int c4 = i & 31;
        int row = r0 + r;
        float4 v = make_float4(0.f, 0.f, 0.f, 0.f);
        if (row < n) {
            v = reinterpret_cast<const float4*>(X)[row * 32 + c4];
            if (rs) { float s = rs[row]; v.x *= s; v.y *= s; v.z *= s; v.w *= s; }
        }
        reinterpret_cast<float4*>(&xs[r][0])[c4] = v;
    }
    __syncthreads();
    const int tx = t & 31, ty = t >> 5;
    const int c0 = tx << 2;
    float acc[4][4] = {};
    const float* wp = W + c0;
    for (int k = 0; k < 128; k += 4) {
        float4 w0 = *reinterpret_cast<const float4*>(wp + (k + 0) * 128);
        float4 w1 = *reinterpret_cast<const float4*>(wp + (k + 1) * 128);
        float4 w2 = *reinterpret_cast<const float4*>(wp + (k + 2) * 128);
        float4 w3 = *reinterpret_cast<const float4*>(wp + (k + 3) * 128);
#pragma unroll
        for (int i = 0; i < 4; ++i) {
            float4 xv = *reinterpret_cast<const float4*>(&xs[ty * 4 + i][k]);
            acc[i][0] += xv.x * w0.x; acc[i][1] += xv.x * w0.y; acc[i][2] += xv.x * w0.z; acc[i][3] += xv.x * w0.w;
            acc[i][0] += xv.y * w1.x; acc[i][1] += xv.y * w1.y; acc[i][2] += xv.y * w1.z; acc[i][3] += xv.y * w1.w;
            acc[i][0] += xv.z * w2.x; acc[i][1] += xv.z * w2.y; acc[i][2] += xv.z * w2.z; acc[i][3] += xv.z * w2.w;
            acc[i][0] += xv.w * w3.x; acc[i][1] += xv.w * w3.y; acc[i][2] += xv.w * w3.z; acc[i][3] += xv.w * w3.w;
        }
    }
    float4 bv = make_float4(0.f, 0.f, 0.f, 0.f);
    if (bias) bv = reinterpret_cast<const float4*>(bias)[tx];
#pragma unroll
    for (int i = 0; i < 4; ++i) {
        int row = r0 + ty * 4 + i;
        if (row < n) {
            float4 o;
            o.x = acc[i][0] + bv.x; o.y = acc[i][1] + bv.y;
            o.z = acc[i][2] + bv.z; o.w = acc[i][3] + bv.w;
            if (RELU) {
                o.x = fmaxf(o.x, 0.f); o.y = fmaxf(o.y, 0.f);
                o.z = fmaxf(o.z, 0.f); o.w = fmaxf(o.w, 0.f);
            }
            reinterpret_cast<float4*>(out)[row * 32 + tx] = o;
        }
    }
}

// ---------------- CSR aggregation: one wave per dst row ----------------
// MODE 0: out = sum (raw, pre-scale optional)
// MODE 1: out = relu(si*sum + b)   (write)
// MODE 2: out += relu(si*sum + b)  (accumulate)

template<int MODE>
static __global__ __launch_bounds__(256)
void agg_kernel(const float* __restrict__ h, const float* __restrict__ pre,
                const int* __restrict__ off, const int* __restrict__ eid,
                const float* __restrict__ si, const float* __restrict__ bias,
                float* __restrict__ out, int n_dst) {
    int row = blockIdx.x * 4 + (threadIdx.x >> 6);
    if (row >= n_dst) return;
    int lane = threadIdx.x & 63;
    int e0 = off[row], e1 = off[row + 1];
    float ax = 0.f, ay = 0.f;
    const float2* h2 = reinterpret_cast<const float2*>(h);
    int j = e0;
    for (; j + 4 <= e1; j += 4) {
        int s0 = eid[j], s1 = eid[j + 1], s2 = eid[j + 2], s3 = eid[j + 3];
        float2 v0 = h2[s0 * 64 + lane];
        float2 v1 = h2[s1 * 64 + lane];
        float2 v2 = h2[s2 * 64 + lane];
        float2 v3 = h2[s3 * 64 + lane];
        if (pre) {
            float p0 = pre[s0], p1 = pre[s1], p2 = pre[s2], p3 = pre[s3];
            ax += v0.x * p0 + v1.x * p1 + v2.x * p2 + v3.x * p3;
            ay += v0.y * p0 + v1.y * p1 + v2.y * p2 + v3.y * p3;
        } else {
            ax += v0.x + v1.x + v2.x + v3.x;
            ay += v0.y + v1.y + v2.y + v3.y;
        }
    }
    for (; j < e1; ++j) {
        int s = eid[j];
        float2 v = h2[s * 64 + lane];
        float pp = pre ? pre[s] : 1.0f;
        ax += v.x * pp; ay += v.y * pp;
    }
    float2* o2 = reinterpret_cast<float2*>(out) + row * 64 + lane;
    if (MODE == 0) {
        *o2 = make_float2(ax, ay);
    } else {
        float s = si[row];
        float2 b = reinterpret_cast<const float2*>(bias)[lane];
        float ox = fmaxf(ax * s + b.x, 0.f);
        float oy = fmaxf(ay * s + b.y, 0.f);
        if (MODE == 2) { float2 cur = *o2; ox += cur.x; oy += cur.y; }
        *o2 = make_float2(ox, oy);
    }
}

// ---------------- orchestration ----------------

extern "C" void kernel_launch(void* const* d_in, const int* in_sizes, int n_in,
                              void* d_out, int out_size, void* d_ws, size_t ws_size,
                              hipStream_t stream) {
    const float* x_cell   = (const float*)d_in[1];
    const float* x_gotem  = (const float*)d_in[2];
    const float* W_eg_c2g = (const float*)d_in[3];  const float* b_eg_c2g = (const float*)d_in[4];
    const float* W_eg_t2g = (const float*)d_in[5];  const float* b_eg_t2g = (const float*)d_in[6];
    const float* W1_g2c   = (const float*)d_in[11]; const float* b1_g2c   = (const float*)d_in[12];
    const float* W1_g2t   = (const float*)d_in[15]; const float* b1_g2t   = (const float*)d_in[16];
    const float* W2_c2g   = (const float*)d_in[21]; const float* b2_c2g   = (const float*)d_in[22];
    const float* W2_t2g   = (const float*)d_in[25]; const float* b2_t2g   = (const float*)d_in[26];
    const float* W3_g2c   = (const float*)d_in[27]; const float* b3_g2c   = (const float*)d_in[28];
    const float* Wd_cell  = (const float*)d_in[29]; const float* bd_cell  = (const float*)d_in[30];
    const int* eg2c_src = (const int*)d_in[31]; const int* eg2c_dst = (const int*)d_in[32];
    const int* ec2g_src = (const int*)d_in[33]; const int* ec2g_dst = (const int*)d_in[34];
    const int* eg2t_src = (const int*)d_in[35]; const int* eg2t_dst = (const int*)d_in[36];
    const int* et2g_src = (const int*)d_in[37]; const int* et2g_dst = (const int*)d_in[38];

    char* p = (char*)d_ws;
    auto alloc = [&](size_t bytes) { char* r = p; p += (bytes + 255) & ~(size_t)255; return r; };
    float* h_buf = (float*)alloc((size_t)NC * 128 * 4);   // scratch h / agg-first A
    float* g_buf = (float*)alloc((size_t)NG * 128 * 4);   // g, then g2
    float* c_buf = (float*)alloc((size_t)NC * 128 * 4);   // c1, then c3
    float* t_buf = (float*)alloc((size_t)NT * 128 * 4);   // t1
    int* off_gc = (int*)alloc((NG + 1) * 4);  int* eid_gc = (int*)alloc((size_t)EGC * 4); // ec2g (dst=gene)
    int* off_gt = (int*)alloc((NG + 1) * 4);  int* eid_gt = (int*)alloc((size_t)EGT * 4); // et2g (dst=gene)
    int* off_c  = (int*)alloc((NC + 1) * 4);  int* eid_c  = (int*)alloc((size_t)EGC * 4); // eg2c (dst=cell)
    int* off_t  = (int*)alloc((NT + 1) * 4);  int* eid_t  = (int*)alloc((size_t)EGT * 4); // eg2t (dst=gotem)
    float* so_ec2g = (float*)alloc(NC * 4);
    float* so_et2g = (float*)alloc(NT * 4);
    float* so_eg2c = (float*)alloc(NG * 4);
    float* so_eg2t = (float*)alloc(NG * 4);
    float* si_ec2g = (float*)alloc(NG * 4);
    float* si_et2g = (float*)alloc(NG * 4);
    float* si_eg2c = (float*)alloc(NC * 4);
    float* si_eg2t = (float*)alloc(NT * 4);
    char* cnt_base = alloc(0);
    int* co_ec2g = (int*)alloc(NC * 4); int* ci_ec2g = (int*)alloc(NG * 4); int* cu_ec2g = (int*)alloc(NG * 4);
    int* co_et2g = (int*)alloc(NT * 4); int* ci_et2g = (int*)alloc(NG * 4); int* cu_et2g = (int*)alloc(NG * 4);
    int* co_eg2c = (int*)alloc(NG * 4); int* ci_eg2c = (int*)alloc(NC * 4); int* cu_eg2c = (int*)alloc(NC * 4);
    int* co_eg2t = (int*)alloc(NG * 4); int* ci_eg2t = (int*)alloc(NT * 4); int* cu_eg2t = (int*)alloc(NT * 4);
    size_t cnt_bytes = (size_t)(p - cnt_base);
    hipMemsetAsync(cnt_base, 0, cnt_bytes, stream);

    auto cdiv = [](int a, int b) { return (a + b - 1) / b; };

    // ---- CSR + degree build (4 edge types, fused) ----
    EdgeSeg ha{ec2g_src, ec2g_dst, EGC, co_ec2g, ci_ec2g};
    EdgeSeg hb{et2g_src, et2g_dst, EGT, co_et2g, ci_et2g};
    EdgeSeg hc{eg2c_src, eg2c_dst, EGC, co_eg2c, ci_eg2c};
    EdgeSeg hd{eg2t_src, eg2t_dst, EGT, co_eg2t, ci_eg2t};
    hist4_kernel<<<cdiv(2 * EGC + 2 * EGT, 256), 256, 0, stream>>>(ha, hb, hc, hd);

    ScaleSeg sa{co_ec2g, so_ec2g, NC, ci_ec2g, si_ec2g, NG, NC};
    ScaleSeg sb{co_et2g, so_et2g, NT, ci_et2g, si_et2g, NG, NG};
    ScaleSeg sc{co_eg2c, so_eg2c, NG, ci_eg2c, si_eg2c, NC, NC};
    ScaleSeg sd{co_eg2t, so_eg2t, NG, ci_eg2t, si_eg2t, NT, NG};
    scales4_kernel<<<cdiv(NC + NG + NC + NG, 256), 256, 0, stream>>>(sa, sb, sc, sd);

    scan4_kernel<<<4, 1024, 0, stream>>>(ci_ec2g, off_gc, NG, ci_et2g, off_gt, NG,
                                         ci_eg2c, off_c, NC, ci_eg2t, off_t, NT);

    FillSeg fa{ec2g_src, ec2g_dst, EGC, off_gc, cu_ec2g, eid_gc};
    FillSeg fb{et2g_src, et2g_dst, EGT, off_gt, cu_et2g, eid_gt};
    FillSeg fc{eg2c_src, eg2c_dst, EGC, off_c, cu_eg2c, eid_c};
    FillSeg fd{eg2t_src, eg2t_dst, EGT, off_t, cu_eg2t, eid_t};
    fill4_kernel<<<cdiv(2 * EGC + 2 * EGT, 256), 256, 0, stream>>>(fa, fb, fc, fd);

    // ---- Layer E: g = relu(gconv(x_cell via ec2g) + gconv(x_gotem via et2g)) ----
    agg_kernel<0><<<cdiv(NG, 4), 256, 0, stream>>>(x_cell, so_ec2g, off_gc, eid_gc, nullptr, nullptr, h_buf, NG);
    gemm_kernel<1><<<cdiv(NG, 32), 256, 0, stream>>>(h_buf, si_ec2g, W_eg_c2g, b_eg_c2g, g_buf, NG);
    gemm_kernel<0><<<cdiv(NT, 32), 256, 0, stream>>>(x_gotem, so_et2g, W_eg_t2g, nullptr, h_buf, NT);
    agg_kernel<2><<<cdiv(NG, 4), 256, 0, stream>>>(h_buf, nullptr, off_gt, eid_gt, si_et2g, b_eg_t2g, g_buf, NG);

    // ---- c1 = gconv(g via eg2c): gemm-first ----
    gemm_kernel<0><<<cdiv(NG, 32), 256, 0, stream>>>(g_buf, so_eg2c, W1_g2c, nullptr, h_buf, NG);
    agg_kernel<1><<<cdiv(NC, 4), 256, 0, stream>>>(h_buf, nullptr, off_c, eid_c, si_eg2c, b1_g2c, c_buf, NC);

    // ---- t1 = gconv(g via eg2t): agg-first ----
    agg_kernel<0><<<cdiv(NT, 4), 256, 0, stream>>>(g_buf, so_eg2t, off_t, eid_t, nullptr, nullptr, h_buf, NT);
    gemm_kernel<1><<<cdiv(NT, 32), 256, 0, stream>>>(h_buf, si_eg2t, W1_g2t, b1_g2t, t_buf, NT);

    // ---- g2 = gconv(c1 via ec2g) + gconv(t1 via et2g) ----
    agg_kernel<0><<<cdiv(NG, 4), 256, 0, stream>>>(c_buf, so_ec2g, off_gc, eid_gc, nullptr, nullptr, h_buf, NG);
    gemm_kernel<1><<<cdiv(NG, 32), 256, 0, stream>>>(h_buf, si_ec2g, W2_c2g, b2_c2g, g_buf, NG);
    gemm_kernel<0><<<cdiv(NT, 32), 256, 0, stream>>>(t_buf, so_et2g, W2_t2g, nullptr, h_buf, NT);
    agg_kernel<2><<<cdiv(NG, 4), 256, 0, stream>>>(h_buf, nullptr, off_gt, eid_gt, si_et2g, b2_t2g, g_buf, NG);

    // ---- c3 = gconv(g2 via eg2c) ----
    gemm_kernel<0><<<cdiv(NG, 32), 256, 0, stream>>>(g_buf, so_eg2c, W3_g2c, nullptr, h_buf, NG);
    agg_kernel<1><<<cdiv(NC, 4), 256, 0, stream>>>(h_buf, nullptr, off_c, eid_c, si_eg2c, b3_g2c, c_buf, NC);

    // ---- out = c3 @ Wd_cell + bd_cell ----
    gemm_kernel<0><<<cdiv(NC, 32), 256, 0, stream>>>(c_buf, nullptr, Wd_cell, bd_cell, (float*)d_out, NC);
}